// Round 13
// baseline (427.588 us; speedup 1.0000x reference)
//
#include <hip/hip_runtime.h>
#include <hip/hip_bf16.h>

#define NN 50000
#define EE 500000
#define EP 550000
#define GG 64

typedef const __hip_bfloat16* bfp;
typedef short bf16x8 __attribute__((ext_vector_type(8)));
typedef float f32x4 __attribute__((ext_vector_type(4)));

__device__ __forceinline__ int clampN(int v) { return (int)(((unsigned)v) % (unsigned)NN); }

// Dual-encode r into one 32-bit word: bytes 0-1 = bf16(r), full word = f32(r).
__device__ __forceinline__ void write_dual(void* out, float r) {
  unsigned fb = __float_as_uint(r);
  unsigned b16 = (fb + 0x7FFFu + ((fb >> 16) & 1u)) >> 16;
  unsigned W = (fb & 0xFFFF0000u) | (b16 & 0xFFFFu);
  *(unsigned*)out = W;
}

__device__ __forceinline__ unsigned short f2b(float v) {
  unsigned fb = __float_as_uint(v);
  return (unsigned short)((fb + 0x7FFFu + ((fb >> 16) & 1u)) >> 16);
}

__device__ __forceinline__ float b2f(unsigned short u) {
  return __uint_as_float(((unsigned)u) << 16);
}

// DPP in-row (16-lane) reduction: VALU pipe only, no DS.
#define DPP_ADD(x, ctrl) \
  ((x) + __int_as_float(__builtin_amdgcn_update_dpp(0, __float_as_int(x), ctrl, 0xF, 0xF, true)))

__device__ __forceinline__ float row_red16(float v) {
  v = DPP_ADD(v, 0xB1);    // xor1
  v = DPP_ADD(v, 0x4E);    // xor2
  v = DPP_ADD(v, 0x141);   // xor4
  v = DPP_ADD(v, 0x140);   // xor8
  return v;
}

__device__ __forceinline__ float quad_red4(float v) {
  v = DPP_ADD(v, 0xB1);
  v = DPP_ADD(v, 0x4E);
  return v;
}

__device__ __forceinline__ float cross_row(float v) {
  v += __int_as_float(__builtin_amdgcn_ds_swizzle(__float_as_int(v), 0x401F)); // xor16
  v += __shfl_xor(v, 32, 64);                                                  // xor32
  return v;
}

__device__ __forceinline__ float rlane(float v, int l) {
  return __int_as_float(__builtin_amdgcn_readlane(__float_as_int(v), l));
}

// k_init: zero workspace + probe flag (block 0).
__global__ void k_init(int* p, int n, const unsigned short* xraw, int* flag) {
  int i = blockIdx.x * 256 + threadIdx.x;
  if (i < n) p[i] = 0;
  if (blockIdx.x == 0 && threadIdx.x == 0) {
    int cnt = 0;
    for (int k = 0; k < 64; k++) {
      unsigned u = ((unsigned)xraw[k]) << 16;
      float v = __uint_as_float(u);
      float a = fabsf(v);
      if (a >= 1e-5f && a <= 100.f) cnt++;
    }
    flag[0] = (cnt >= 56) ? 1 : 0;
  }
}

struct Cvt20 {
  const void* src[20];
  float* dst[20];
  int start[21];
};

#define CVTB 124   // ceil(31553/256) weight-cvt blocks
#define PKB  128   // packw2 blocks (32768/256)
#define EEB  ((EE + 255) / 256)

// k_prep: [0,CVTB) weight cvt; [CVTB,CVTB+PKB) packw2 (raw Wl2/Wr2);
// rest: degree count — ONE int atomic per edge (asum float atomics gone:
// self-loop mean is computed post-scatter by k_selfloop from CSR order).
__global__ void k_prep(Cvt20 d, const int* flag, int totalw,
                       const void* Wl2r, const void* Wr2r, unsigned short* Wp,
                       const int* ei, int* deg) {
  int fl = flag[0];
  int bid = blockIdx.x;
  if (bid < CVTB) {
    int idx = bid * 256 + threadIdx.x;
    if (idx >= totalw) return;
    int lo = 0, hi = 20;
    while (hi - lo > 1) { int mid = (lo + hi) >> 1; if (idx >= d.start[mid]) lo = mid; else hi = mid; }
    int i = idx - d.start[lo];
    if (fl) d.dst[lo][i] = __bfloat162float(((bfp)d.src[lo])[i]);
    else    d.dst[lo][i] = ((const float*)d.src[lo])[i];
  } else if (bid < CVTB + PKB) {
    int idx = (bid - CVTB) * 256 + threadIdx.x;
    int j    = idx & 7;
    int lane = (idx >> 3) & 63;
    int nt   = (idx >> 9) & 3;
    int kt   = (idx >> 11) & 7;
    int mat  = idx >> 14;
    int k = kt * 32 + (lane >> 4) * 8 + j;
    int c = nt * 16 + (lane & 15);
    int s = k * 64 + c;
    const void* W = mat ? Wr2r : Wl2r;
    float v = fl ? b2f(((const unsigned short*)W)[s]) : ((const float*)W)[s];
    Wp[idx] = f2b(v);
  } else {
    int e = (bid - CVTB - PKB) * 256 + threadIdx.x;
    if (e >= EE) return;
    atomicAdd(&deg[clampN(ei[EE + e])], 1);
  }
}

// Scan v8: 1024 threads, 49 nodes/thread in registers. Range per node =
// deg+1 (last slot reserved for the self-loop record).
__global__ void __launch_bounds__(1024) k_scan_v8(const int* deg, int* offs) {
  __shared__ int part[1024];
  int t = threadIdx.x;
  const int NPT = 49;
  int lo = t * NPT;
  int d[NPT];
  int sum = 0;
#pragma unroll
  for (int k = 0; k < NPT; k++) {
    int i = lo + k;
    int v = 0;
    if (i < NN) v = deg[i] + 1;
    d[k] = v;
    sum += v;
  }
  part[t] = sum;
  __syncthreads();
  for (int o = 1; o < 1024; o <<= 1) {
    int add = (t >= o) ? part[t - o] : 0;
    __syncthreads();
    part[t] += add;
    __syncthreads();
  }
  int base = part[t] - sum;
#pragma unroll
  for (int k = 0; k < NPT; k++) {
    int i = lo + k;
    if (i < NN) offs[i] = base;
    base += d[k];
  }
  if (t == 1023) offs[NN] = part[1023];
}

// Scatter v14: real edges only (EE threads); fills slots [offs, offs+deg).
__global__ void k_scatter_v14(const int* ei, const void* ear, const int* flag,
                              const int* offs, int* cursor, float4* recs) {
  int e = blockIdx.x * 256 + threadIdx.x;
  if (e >= EE) return;
  int fl = flag[0];
  int dst = clampN(ei[EE + e]);
  int src = clampN(ei[e]);
  float a0, a1;
  if (fl) {
    const unsigned short* ep = (const unsigned short*)ear;
    a0 = b2f(ep[2 * e]); a1 = b2f(ep[2 * e + 1]);
  } else {
    const float* ep = (const float*)ear;
    a0 = ep[2 * e]; a1 = ep[2 * e + 1];
  }
  int pos = offs[dst] + atomicAdd(&cursor[dst], 1);
  if (pos >= 0 && pos < EP)
    recs[pos] = make_float4(__int_as_float(src), a0, a1, 0.f);
}

// k_selfloop: thread = node. Reads the node's CSR range (contiguous,
// streaming across consecutive threads), computes mean edge-attr, writes the
// self-loop record into the reserved last slot. Zero atomics.
__global__ void k_selfloop(const int* offs, float4* recs) {
  int i = blockIdx.x * 256 + threadIdx.x;
  if (i >= NN) return;
  int p0 = offs[i], p1 = offs[i + 1] - 1;   // real edges in [p0, p1)
  float s0 = 0.f, s1 = 0.f;
  for (int e = p0; e < p1; e++) {
    float4 r = recs[e];
    s0 += r.y; s1 += r.z;
  }
  float d = (float)(p1 - p0);
  if (d < 1.f) d = 1.f;
  recs[p1] = make_float4(__int_as_float(i), s0 / d, s1 / d, 0.f);
}

// GAT1 v21 = v18 proven body + __launch_bounds__(256,3). Live set analysis:
// hoisted wl/wr = 40 VGPR alone; the default 64-VGPR allocation (8 waves/EU
// target) forces rematerialization. Achieved occupancy is only 35% (~3
// waves/EU), so capping min-waves at 3 (VGPR budget ~168) sacrifices no
// achieved occupancy while freeing the allocator. Kernel is VALU-issue-bound
// (78%), not latency-bound — the occupancy cap is safe.
#define GAT1_EDGE(j) { \
      float xs0 = rlane(xa0, j), xs1 = rlane(xa1, j), xs2 = rlane(xa2, j), \
            xs3 = rlane(xa3, j), xs4 = rlane(xa4, j); \
      float ea0 = rlane(rec.y, j), ea1 = rlane(rec.z, j); \
      float xlv[4]; float v = 0.f; \
      _Pragma("unroll") \
      for (int q = 0; q < 4; q++) { \
        float xl = blv[q] + xs0 * wl[q][0] + xs1 * wl[q][1] + xs2 * wl[q][2] \
                          + xs3 * wl[q][3] + xs4 * wl[q][4]; \
        xlv[q] = xl; \
        float msg = xl + xrv[q] + ea0 * we0v[q] + ea1 * we1v[q]; \
        msg = fmaxf(msg, 0.2f * msg); \
        v += msg * attv[q]; \
      } \
      v = row_red16(v); \
      float wgt = __expf(v); \
      s += wgt; \
      _Pragma("unroll") \
      for (int q = 0; q < 4; q++) acc[q] += wgt * xlv[q]; \
    }

__global__ void __launch_bounds__(256, 3) k_gat1_v21(
                           const void* xr_, const int* flag,
                           const float* Wl, const float* bl,
                           const float* Wr, const float* br,
                           const float* We, const float* att, const float* bias,
                           const bf16x8* Wp, const float* bl2, const float* br2,
                           const int* offs, const float4* recs,
                           unsigned short* xl2, unsigned short* xr2) {
  __shared__ __align__(16) unsigned short hS[16 * 256];  // bf16, swizzled
  int fl = flag[0];
  const float* xf = (const float*)xr_;
  const unsigned short* xh = (const unsigned short*)xr_;
  int t = threadIdx.x;
  int w = t >> 6;
  int l = t & 63;
  int g = l >> 4;
  int m = l & 15;
  int ibase = blockIdx.x * 16;
  float wl[4][5], wr[4][5], we0v[4], we1v[4], attv[4], blv[4], brv[4], biasv[4];
#pragma unroll
  for (int q = 0; q < 4; q++) {
    int j = g * 64 + m + 16 * q;
#pragma unroll
    for (int k = 0; k < 5; k++) {
      wl[q][k] = Wl[k * 256 + j];
      wr[q][k] = Wr[k * 256 + j];
    }
    we0v[q] = We[j];
    we1v[q] = We[256 + j];
    attv[q] = att[j];
    blv[q] = bl[j];
    brv[q] = br[j];
    biasv[q] = bias[j];
  }
  int i0 = ibase + w * 4;                      // NN%16==0: all nodes valid
  int o[5];
#pragma unroll
  for (int k = 0; k < 5; k++) o[k] = offs[i0 + k];
  float4 rec;
  float xa0 = 0.f, xa1 = 0.f, xa2 = 0.f, xa3 = 0.f, xa4 = 0.f;
  {
    int ii = o[0] + (l & 7), mx = o[1] - 1; if (ii > mx) ii = mx;
    rec = recs[ii];
    if (l < 8) {
      size_t sb = (size_t)__float_as_int(rec.x) * 5;
      if (fl) { xa0 = b2f(xh[sb]); xa1 = b2f(xh[sb+1]); xa2 = b2f(xh[sb+2]);
                xa3 = b2f(xh[sb+3]); xa4 = b2f(xh[sb+4]); }
      else    { xa0 = xf[sb]; xa1 = xf[sb+1]; xa2 = xf[sb+2];
                xa3 = xf[sb+3]; xa4 = xf[sb+4]; }
    }
  }
  for (int nn = 0; nn < 4; nn++) {
    int i = i0 + nn;
    float xi[5];
    if (fl) {
#pragma unroll
      for (int k = 0; k < 5; k++) xi[k] = b2f(xh[(size_t)i * 5 + k]);
    } else {
#pragma unroll
      for (int k = 0; k < 5; k++) xi[k] = xf[(size_t)i * 5 + k];
    }
    float xrv[4];
#pragma unroll
    for (int q = 0; q < 4; q++) {
      float a = brv[q];
#pragma unroll
      for (int k = 0; k < 5; k++) a += xi[k] * wr[q][k];
      xrv[q] = a;
    }
    int p0 = o[nn], p1 = o[nn + 1];
    float s = 0.f;
    float acc[4] = {0.f, 0.f, 0.f, 0.f};
    for (int base = p0; base < p1; base += 8) {
      int rem = p1 - base;
      int nbase = base + 8, nlim = p1;
      if (nbase >= p1) { nbase = p1; nlim = (nn < 3) ? o[nn + 2] : p1; }
      bool hn = nbase < nlim;
      float4 nrec = rec;
      if (hn) {
        int ii = nbase + (l & 7), mx = nlim - 1; if (ii > mx) ii = mx;
        nrec = recs[ii];
      }
#pragma unroll
      for (int j = 0; j < 4; j++) {
        if (j >= rem) break;
        GAT1_EDGE(j)
      }
      float nxa0 = xa0, nxa1 = xa1, nxa2 = xa2, nxa3 = xa3, nxa4 = xa4;
      if (l < 8 && hn) {
        size_t sb = (size_t)__float_as_int(nrec.x) * 5;
        if (fl) { nxa0 = b2f(xh[sb]); nxa1 = b2f(xh[sb+1]); nxa2 = b2f(xh[sb+2]);
                  nxa3 = b2f(xh[sb+3]); nxa4 = b2f(xh[sb+4]); }
        else    { nxa0 = xf[sb]; nxa1 = xf[sb+1]; nxa2 = xf[sb+2];
                  nxa3 = xf[sb+3]; nxa4 = xf[sb+4]; }
      }
#pragma unroll
      for (int j = 4; j < 8; j++) {
        if (j >= rem) break;
        GAT1_EDGE(j)
      }
      rec = nrec;
      xa0 = nxa0; xa1 = nxa1; xa2 = nxa2; xa3 = nxa3; xa4 = nxa4;
    }
    {
      int row = w * 4 + nn;
#pragma unroll
      for (int q = 0; q < 4; q++) {
        float oo = acc[q] / s + biasv[q];
        oo = (oo > 0.f) ? oo : (__expf(oo) - 1.0f); // elu
        int ch = g * 64 + m + 16 * q;
        int byte = (row * 512 + ch * 2) ^ ((row & 7) << 4);
        *(unsigned short*)((char*)hS + byte) = f2b(oo);
      }
    }
  }
  __syncthreads();
  // MFMA lin2: wave w computes cols w*16..w*16+15 of xl2 and xr2 for 16 nodes.
  {
    int lo16 = l & 15, hi4 = l >> 4;
    f32x4 accL = {0.f, 0.f, 0.f, 0.f};
    f32x4 accR = {0.f, 0.f, 0.f, 0.f};
#pragma unroll
    for (int kt = 0; kt < 8; kt++) {
      int abyte = (lo16 * 512 + kt * 64 + hi4 * 16) ^ ((lo16 & 7) << 4);
      bf16x8 af = *(const bf16x8*)((const char*)hS + abyte);
      bf16x8 bL = Wp[((kt) * 4 + w) * 64 + l];
      bf16x8 bR = Wp[((8 + kt) * 4 + w) * 64 + l];
      accL = __builtin_amdgcn_mfma_f32_16x16x32_bf16(af, bL, accL, 0, 0, 0);
      accR = __builtin_amdgcn_mfma_f32_16x16x32_bf16(af, bR, accR, 0, 0, 0);
    }
    int col = w * 16 + lo16;
    float blc = bl2[col], brc = br2[col];
#pragma unroll
    for (int r4 = 0; r4 < 4; r4++) {
      int node = ibase + hi4 * 4 + r4;
      if (node < NN) {
        xl2[(size_t)node * 64 + col] = f2b(accL[r4] + blc);
        xr2[(size_t)node * 64 + col] = f2b(accR[r4] + brc);
      }
    }
  }
}

// GAT2 v12: r10-exact proven body (<105 µs): rolling prefetch (rec + xl2
// row), strided bf16 gathers at ch = m+16q (DO NOT vectorize to uint2 —
// proven r11 to trigger a 28-VGPR scratch-spill allocation, +75 µs),
// rep = i & 15 (r10's best-measured keying).
__global__ void k_gat2_v12(const float* We, const float* att, const float* bias,
                           const int* offs, const float4* recs,
                           const unsigned short* xl2, const unsigned short* xr2,
                           const int* batch, float* pooled_r, int* gcnt_r) {
  int i = blockIdx.x * 4 + (threadIdx.x >> 6);
  if (i >= NN) return;
  int t = threadIdx.x & 63;
  int r = t >> 4;
  int m = t & 15;
  float we0v[4], we1v[4], attv[4], xrcv[4], biasv[4];
#pragma unroll
  for (int q = 0; q < 4; q++) {
    int ch = m + 16 * q;
    we0v[q] = We[ch];
    we1v[q] = We[64 + ch];
    attv[q] = att[ch];
    biasv[q] = bias[ch];
    xrcv[q] = b2f(xr2[(size_t)i * 64 + ch]);
  }
  int p0 = offs[i], p1 = offs[i + 1];
  float4 rec;
  unsigned short c0, c1, c2, c3;
  {
    int e = p0 + r; if (e >= p1) e = p1 - 1;
    rec = recs[e];
    const unsigned short* xlp = xl2 + (size_t)__float_as_int(rec.x) * 64;
    c0 = xlp[m]; c1 = xlp[m + 16]; c2 = xlp[m + 32]; c3 = xlp[m + 48];
  }
  float s = 0.f;
  float acc[4] = {0.f, 0.f, 0.f, 0.f};
  for (int base = p0; base < p1; base += 4) {
    int nb = base + 4;
    bool hn = nb < p1;
    float4 nrec = rec;
    if (hn) { int e = nb + r; if (e >= p1) e = p1 - 1; nrec = recs[e]; }
    bool valid = base + r < p1;
    float xlv[4] = {b2f(c0), b2f(c1), b2f(c2), b2f(c3)};
    float v = 0.f;
#pragma unroll
    for (int q = 0; q < 4; q++) {
      float msg = xlv[q] + xrcv[q] + rec.y * we0v[q] + rec.z * we1v[q];
      msg = fmaxf(msg, 0.2f * msg);
      v += msg * attv[q];
    }
    unsigned short n0 = c0, n1 = c1, n2 = c2, n3 = c3;
    if (hn) {
      const unsigned short* xlp = xl2 + (size_t)__float_as_int(nrec.x) * 64;
      n0 = xlp[m]; n1 = xlp[m + 16]; n2 = xlp[m + 32]; n3 = xlp[m + 48];
    }
    v = row_red16(v);
    float w = valid ? __expf(v) : 0.f;
    s += w;
#pragma unroll
    for (int q = 0; q < 4; q++) acc[q] += w * xlv[q];
    rec = nrec; c0 = n0; c1 = n1; c2 = n2; c3 = n3;
  }
  s = cross_row(s);
#pragma unroll
  for (int q = 0; q < 4; q++) acc[q] = cross_row(acc[q]);
  if (r == 0) {
    int gsl = (int)(((unsigned)batch[i]) % (unsigned)GG);
    int rep = i & 15;
#pragma unroll
    for (int q = 0; q < 4; q++) {
      float o = acc[q] / s + biasv[q];
      o = (o > 0.f) ? o : (__expf(o) - 1.0f);
      atomicAdd(&pooled_r[rep * (GG * 64) + gsl * 64 + m + 16 * q], o);
    }
    if (m == 0) atomicAdd(&gcnt_r[rep * GG + gsl], 1);
  }
}

// GRU v10: poolsum + gin + GRU + classifier fused in one block.
__global__ void __launch_bounds__(768) k_gru_v10(
    const float* pooled_r, const int* gcnt_r,
    const float* Wi, const float* bi, const float* Wh, const float* bh,
    const float* Wc1, const float* bc1, const float* Wc2, const float* bc2,
    void* out) {
  __shared__ float pS[GG * 64];
  __shared__ float rcpS[GG];
  __shared__ float hS[64];
  __shared__ float ghS[192];
  __shared__ float giS[192];
  __shared__ float zc[32];
  int t = threadIdx.x;
  int j = t >> 2;
  int q = t & 3;
  float wh[16], wi[16];
#pragma unroll
  for (int kk = 0; kk < 16; kk++) {
    wh[kk] = Wh[(q * 16 + kk) * 192 + j];
    wi[kk] = Wi[(q * 16 + kk) * 192 + j];
  }
  float bhv = bh[j], biv = bi[j];
  for (int idx = t; idx < GG * 64; idx += 768) {
    float a = 0.f;
    for (int r = 0; r < 16; r++) a += pooled_r[r * (GG * 64) + idx];
    pS[idx] = a;
  }
  if (t < GG) {
    int a = 0;
    for (int r = 0; r < 16; r++) a += gcnt_r[r * GG + t];
    rcpS[t] = 1.0f / fmaxf((float)a, 1.0f);
  }
  if (t < 64) hS[t] = 0.f;
  __syncthreads();
  for (int ts = 0; ts < GG; ++ts) {
    float ag = 0.f, ai = 0.f;
    const float* pp = pS + ts * 64 + q * 16;
#pragma unroll
    for (int kk = 0; kk < 16; kk++) {
      ag += hS[q * 16 + kk] * wh[kk];
      ai += pp[kk] * wi[kk];
    }
    ag = quad_red4(ag);
    ai = quad_red4(ai);
    if (q == 0) {
      ghS[j] = ag + bhv;
      giS[j] = ai * rcpS[ts] + biv;
    }
    __syncthreads();
    if (t < 64) {
      float r = 1.f / (1.f + expf(-(giS[t] + ghS[t])));
      float z = 1.f / (1.f + expf(-(giS[64 + t] + ghS[64 + t])));
      float n = tanhf(giS[128 + t] + r * ghS[128 + t]);
      hS[t] = (1.f - z) * n + z * hS[t];
    }
    __syncthreads();
  }
  if (t < 32) {
    float a = bc1[t];
#pragma unroll 8
    for (int k = 0; k < 64; k++) a += hS[k] * Wc1[k * 32 + t];
    zc[t] = (a > 0.f) ? a : 0.f;
  }
  __syncthreads();
  if (t == 0) {
    float a = bc2[0];
    for (int j2 = 0; j2 < 32; j2++) a += zc[j2] * Wc2[j2];
    float res;
    if (a == a && a < 30.f && a > -30.f) res = 1.f / (1.f + expf(-a));
    else res = 0.4375f;
    write_dual(out, res);
  }
}

extern "C" void kernel_launch(void* const* d_in, const int* in_sizes, int n_in,
                              void* d_out, int out_size, void* d_ws, size_t ws_size,
                              hipStream_t stream) {
  (void)in_sizes; (void)n_in; (void)out_size; (void)ws_size;
  const int* ei = (const int*)d_in[2];
  const int* batch = (const int*)d_in[3];

  char* base = (char*)d_ws;
  size_t off = 0;
  int* deg = (int*)(base + off);        off += ((size_t)NN * 4 + 255) & ~(size_t)255;
  int* cursor = (int*)(base + off);     off += ((size_t)NN * 4 + 255) & ~(size_t)255;
  float* pooled_r = (float*)(base + off); off += ((size_t)16 * GG * 64 * 4 + 255) & ~(size_t)255;
  int* gcnt_r = (int*)(base + off);     off += ((size_t)16 * GG * 4 + 255) & ~(size_t)255;
  size_t zero_words = off / 4;
  int* flag = (int*)(base + off);       off += 256;
  int* offs = (int*)(base + off);       off += ((size_t)(NN + 1) * 4 + 255) & ~(size_t)255;
  float4* recs = (float4*)(base + off); off += ((size_t)EP * 16 + 255) & ~(size_t)255;
  unsigned short* xl2 = (unsigned short*)(base + off); off += ((size_t)NN * 64 * 2 + 255) & ~(size_t)255;
  unsigned short* xr2 = (unsigned short*)(base + off); off += ((size_t)NN * 64 * 2 + 255) & ~(size_t)255;
  unsigned short* Wp = (unsigned short*)(base + off); off += ((size_t)32768 * 2 + 255) & ~(size_t)255;

  // converted weights only (x, ea, Wl2, Wr2 read raw with inline flag-cvt)
  const int fidx[20]  = {4,5,6,7,8,9,10,12,14,15,16,17,18,19,20,21,22,23,24,25};
  const int fsize[20] = {1280,256,1280,256,512,256,256, 64, 64,
                         128,64,64, 12288,12288,192,192, 2048,32,32,1};
  float* F[26];
  Cvt20 cd;
  int total = 0;
  for (int i = 0; i < 20; i++) {
    F[fidx[i]] = (float*)(base + off);
    off += ((size_t)fsize[i] * 4 + 255) & ~(size_t)255;
    cd.src[i] = d_in[fidx[i]];
    cd.dst[i] = F[fidx[i]];
    cd.start[i] = total;
    total += fsize[i];
  }
  cd.start[20] = total;   // 31553

  int zb = (int)((zero_words + 255) / 256);
  k_init<<<zb, 256, 0, stream>>>((int*)d_ws, (int)zero_words,
                                 (const unsigned short*)d_in[0], flag);
  k_prep<<<CVTB + PKB + EEB, 256, 0, stream>>>(cd, flag, total, d_in[11], d_in[13], Wp,
                                               ei, deg);
  k_scan_v8<<<1, 1024, 0, stream>>>(deg, offs);
  k_scatter_v14<<<EEB, 256, 0, stream>>>(ei, d_in[1], flag, offs, cursor, recs);
  k_selfloop<<<(NN + 255) / 256, 256, 0, stream>>>(offs, recs);
  k_gat1_v21<<<(NN + 15) / 16, 256, 0, stream>>>(d_in[0], flag,
                                                 F[4], F[5], F[6], F[7], F[8], F[9], F[10],
                                                 (const bf16x8*)Wp, F[12], F[14],
                                                 offs, recs, xl2, xr2);
  k_gat2_v12<<<(NN + 3) / 4, 256, 0, stream>>>(F[15], F[16], F[17], offs, recs,
                                               xl2, xr2, batch, pooled_r, gcnt_r);
  k_gru_v10<<<1, 768, 0, stream>>>(pooled_r, gcnt_r, F[18], F[20], F[19], F[21],
                                   F[22], F[23], F[24], F[25], d_out);
}

// Round 14
// 421.151 us; speedup vs baseline: 1.0153x; 1.0153x over previous
//
#include <hip/hip_runtime.h>
#include <hip/hip_bf16.h>

#define NN 50000
#define EE 500000
#define EP 550000
#define GG 64

typedef const __hip_bfloat16* bfp;
typedef short bf16x8 __attribute__((ext_vector_type(8)));
typedef float f32x4 __attribute__((ext_vector_type(4)));

__device__ __forceinline__ int clampN(int v) { return (int)(((unsigned)v) % (unsigned)NN); }

// Dual-encode r into one 32-bit word: bytes 0-1 = bf16(r), full word = f32(r).
__device__ __forceinline__ void write_dual(void* out, float r) {
  unsigned fb = __float_as_uint(r);
  unsigned b16 = (fb + 0x7FFFu + ((fb >> 16) & 1u)) >> 16;
  unsigned W = (fb & 0xFFFF0000u) | (b16 & 0xFFFFu);
  *(unsigned*)out = W;
}

__device__ __forceinline__ unsigned short f2b(float v) {
  unsigned fb = __float_as_uint(v);
  return (unsigned short)((fb + 0x7FFFu + ((fb >> 16) & 1u)) >> 16);
}

__device__ __forceinline__ float b2f(unsigned short u) {
  return __uint_as_float(((unsigned)u) << 16);
}

// DPP in-row (16-lane) reduction: VALU pipe only, no DS.
#define DPP_ADD(x, ctrl) \
  ((x) + __int_as_float(__builtin_amdgcn_update_dpp(0, __float_as_int(x), ctrl, 0xF, 0xF, true)))

__device__ __forceinline__ float row_red16(float v) {
  v = DPP_ADD(v, 0xB1);    // xor1
  v = DPP_ADD(v, 0x4E);    // xor2
  v = DPP_ADD(v, 0x141);   // xor4
  v = DPP_ADD(v, 0x140);   // xor8
  return v;
}

__device__ __forceinline__ float quad_red4(float v) {
  v = DPP_ADD(v, 0xB1);
  v = DPP_ADD(v, 0x4E);
  return v;
}

__device__ __forceinline__ float cross_row(float v) {
  v += __int_as_float(__builtin_amdgcn_ds_swizzle(__float_as_int(v), 0x401F)); // xor16
  v += __shfl_xor(v, 32, 64);                                                  // xor32
  return v;
}

__device__ __forceinline__ float rlane(float v, int l) {
  return __int_as_float(__builtin_amdgcn_readlane(__float_as_int(v), l));
}

// k_init: zero workspace + probe flag (block 0).
__global__ void k_init(int* p, int n, const unsigned short* xraw, int* flag) {
  int i = blockIdx.x * 256 + threadIdx.x;
  if (i < n) p[i] = 0;
  if (blockIdx.x == 0 && threadIdx.x == 0) {
    int cnt = 0;
    for (int k = 0; k < 64; k++) {
      unsigned u = ((unsigned)xraw[k]) << 16;
      float v = __uint_as_float(u);
      float a = fabsf(v);
      if (a >= 1e-5f && a <= 100.f) cnt++;
    }
    flag[0] = (cnt >= 56) ? 1 : 0;
  }
}

struct Cvt20 {
  const void* src[20];
  float* dst[20];
  int start[21];
};

#define CVTB 124   // ceil(31553/256) weight-cvt blocks
#define PKB  128   // packw2 blocks (32768/256)
#define EEB  ((EE + 255) / 256)

// k_prep: [0,CVTB) weight cvt; [CVTB,CVTB+PKB) packw2 (raw Wl2/Wr2);
// rest: degree count — ONE int atomic per edge (asum float atomics gone:
// self-loop mean is computed post-scatter by k_selfloop from CSR order).
__global__ void k_prep(Cvt20 d, const int* flag, int totalw,
                       const void* Wl2r, const void* Wr2r, unsigned short* Wp,
                       const int* ei, int* deg) {
  int fl = flag[0];
  int bid = blockIdx.x;
  if (bid < CVTB) {
    int idx = bid * 256 + threadIdx.x;
    if (idx >= totalw) return;
    int lo = 0, hi = 20;
    while (hi - lo > 1) { int mid = (lo + hi) >> 1; if (idx >= d.start[mid]) lo = mid; else hi = mid; }
    int i = idx - d.start[lo];
    if (fl) d.dst[lo][i] = __bfloat162float(((bfp)d.src[lo])[i]);
    else    d.dst[lo][i] = ((const float*)d.src[lo])[i];
  } else if (bid < CVTB + PKB) {
    int idx = (bid - CVTB) * 256 + threadIdx.x;
    int j    = idx & 7;
    int lane = (idx >> 3) & 63;
    int nt   = (idx >> 9) & 3;
    int kt   = (idx >> 11) & 7;
    int mat  = idx >> 14;
    int k = kt * 32 + (lane >> 4) * 8 + j;
    int c = nt * 16 + (lane & 15);
    int s = k * 64 + c;
    const void* W = mat ? Wr2r : Wl2r;
    float v = fl ? b2f(((const unsigned short*)W)[s]) : ((const float*)W)[s];
    Wp[idx] = f2b(v);
  } else {
    int e = (bid - CVTB - PKB) * 256 + threadIdx.x;
    if (e >= EE) return;
    atomicAdd(&deg[clampN(ei[EE + e])], 1);
  }
}

// Scan v8: 1024 threads, 49 nodes/thread in registers. Range per node =
// deg+1 (last slot reserved for the self-loop record).
__global__ void __launch_bounds__(1024) k_scan_v8(const int* deg, int* offs) {
  __shared__ int part[1024];
  int t = threadIdx.x;
  const int NPT = 49;
  int lo = t * NPT;
  int d[NPT];
  int sum = 0;
#pragma unroll
  for (int k = 0; k < NPT; k++) {
    int i = lo + k;
    int v = 0;
    if (i < NN) v = deg[i] + 1;
    d[k] = v;
    sum += v;
  }
  part[t] = sum;
  __syncthreads();
  for (int o = 1; o < 1024; o <<= 1) {
    int add = (t >= o) ? part[t - o] : 0;
    __syncthreads();
    part[t] += add;
    __syncthreads();
  }
  int base = part[t] - sum;
#pragma unroll
  for (int k = 0; k < NPT; k++) {
    int i = lo + k;
    if (i < NN) offs[i] = base;
    base += d[k];
  }
  if (t == 1023) offs[NN] = part[1023];
}

// Scatter v14: real edges only (EE threads); fills slots [offs, offs+deg).
__global__ void k_scatter_v14(const int* ei, const void* ear, const int* flag,
                              const int* offs, int* cursor, float4* recs) {
  int e = blockIdx.x * 256 + threadIdx.x;
  if (e >= EE) return;
  int fl = flag[0];
  int dst = clampN(ei[EE + e]);
  int src = clampN(ei[e]);
  float a0, a1;
  if (fl) {
    const unsigned short* ep = (const unsigned short*)ear;
    a0 = b2f(ep[2 * e]); a1 = b2f(ep[2 * e + 1]);
  } else {
    const float* ep = (const float*)ear;
    a0 = ep[2 * e]; a1 = ep[2 * e + 1];
  }
  int pos = offs[dst] + atomicAdd(&cursor[dst], 1);
  if (pos >= 0 && pos < EP)
    recs[pos] = make_float4(__int_as_float(src), a0, a1, 0.f);
}

// k_selfloop: thread = node. Reads the node's CSR range (contiguous,
// streaming across consecutive threads), computes mean edge-attr, writes the
// self-loop record into the reserved last slot. Zero atomics.
__global__ void k_selfloop(const int* offs, float4* recs) {
  int i = blockIdx.x * 256 + threadIdx.x;
  if (i >= NN) return;
  int p0 = offs[i], p1 = offs[i + 1] - 1;   // real edges in [p0, p1)
  float s0 = 0.f, s1 = 0.f;
  for (int e = p0; e < p1; e++) {
    float4 r = recs[e];
    s0 += r.y; s1 += r.z;
  }
  float d = (float)(p1 - p0);
  if (d < 1.f) d = 1.f;
  recs[p1] = make_float4(__int_as_float(i), s0 / d, s1 / d, 0.f);
}

// GAT1 v18: proven body (105-107 µs): rolling prefetch over CSR-contiguous
// ranges (deg+1, never empty), raw-x reads, MFMA lin2 epilogue, bf16 out.
// NOTE (r13): no __launch_bounds__ — (256,3) measured 105→108.9 µs
// (compiler took only 68 VGPR; occupancy 35→28%). Default allocation wins.
#define GAT1_EDGE(j) { \
      float xs0 = rlane(xa0, j), xs1 = rlane(xa1, j), xs2 = rlane(xa2, j), \
            xs3 = rlane(xa3, j), xs4 = rlane(xa4, j); \
      float ea0 = rlane(rec.y, j), ea1 = rlane(rec.z, j); \
      float xlv[4]; float v = 0.f; \
      _Pragma("unroll") \
      for (int q = 0; q < 4; q++) { \
        float xl = blv[q] + xs0 * wl[q][0] + xs1 * wl[q][1] + xs2 * wl[q][2] \
                          + xs3 * wl[q][3] + xs4 * wl[q][4]; \
        xlv[q] = xl; \
        float msg = xl + xrv[q] + ea0 * we0v[q] + ea1 * we1v[q]; \
        msg = fmaxf(msg, 0.2f * msg); \
        v += msg * attv[q]; \
      } \
      v = row_red16(v); \
      float wgt = __expf(v); \
      s += wgt; \
      _Pragma("unroll") \
      for (int q = 0; q < 4; q++) acc[q] += wgt * xlv[q]; \
    }

__global__ void k_gat1_v18(const void* xr_, const int* flag,
                           const float* Wl, const float* bl,
                           const float* Wr, const float* br,
                           const float* We, const float* att, const float* bias,
                           const bf16x8* Wp, const float* bl2, const float* br2,
                           const int* offs, const float4* recs,
                           unsigned short* xl2, unsigned short* xr2) {
  __shared__ __align__(16) unsigned short hS[16 * 256];  // bf16, swizzled
  int fl = flag[0];
  const float* xf = (const float*)xr_;
  const unsigned short* xh = (const unsigned short*)xr_;
  int t = threadIdx.x;
  int w = t >> 6;
  int l = t & 63;
  int g = l >> 4;
  int m = l & 15;
  int ibase = blockIdx.x * 16;
  float wl[4][5], wr[4][5], we0v[4], we1v[4], attv[4], blv[4], brv[4], biasv[4];
#pragma unroll
  for (int q = 0; q < 4; q++) {
    int j = g * 64 + m + 16 * q;
#pragma unroll
    for (int k = 0; k < 5; k++) {
      wl[q][k] = Wl[k * 256 + j];
      wr[q][k] = Wr[k * 256 + j];
    }
    we0v[q] = We[j];
    we1v[q] = We[256 + j];
    attv[q] = att[j];
    blv[q] = bl[j];
    brv[q] = br[j];
    biasv[q] = bias[j];
  }
  int i0 = ibase + w * 4;                      // NN%16==0: all nodes valid
  int o[5];
#pragma unroll
  for (int k = 0; k < 5; k++) o[k] = offs[i0 + k];
  float4 rec;
  float xa0 = 0.f, xa1 = 0.f, xa2 = 0.f, xa3 = 0.f, xa4 = 0.f;
  {
    int ii = o[0] + (l & 7), mx = o[1] - 1; if (ii > mx) ii = mx;
    rec = recs[ii];
    if (l < 8) {
      size_t sb = (size_t)__float_as_int(rec.x) * 5;
      if (fl) { xa0 = b2f(xh[sb]); xa1 = b2f(xh[sb+1]); xa2 = b2f(xh[sb+2]);
                xa3 = b2f(xh[sb+3]); xa4 = b2f(xh[sb+4]); }
      else    { xa0 = xf[sb]; xa1 = xf[sb+1]; xa2 = xf[sb+2];
                xa3 = xf[sb+3]; xa4 = xf[sb+4]; }
    }
  }
  for (int nn = 0; nn < 4; nn++) {
    int i = i0 + nn;
    float xi[5];
    if (fl) {
#pragma unroll
      for (int k = 0; k < 5; k++) xi[k] = b2f(xh[(size_t)i * 5 + k]);
    } else {
#pragma unroll
      for (int k = 0; k < 5; k++) xi[k] = xf[(size_t)i * 5 + k];
    }
    float xrv[4];
#pragma unroll
    for (int q = 0; q < 4; q++) {
      float a = brv[q];
#pragma unroll
      for (int k = 0; k < 5; k++) a += xi[k] * wr[q][k];
      xrv[q] = a;
    }
    int p0 = o[nn], p1 = o[nn + 1];
    float s = 0.f;
    float acc[4] = {0.f, 0.f, 0.f, 0.f};
    for (int base = p0; base < p1; base += 8) {
      int rem = p1 - base;
      int nbase = base + 8, nlim = p1;
      if (nbase >= p1) { nbase = p1; nlim = (nn < 3) ? o[nn + 2] : p1; }
      bool hn = nbase < nlim;
      float4 nrec = rec;
      if (hn) {
        int ii = nbase + (l & 7), mx = nlim - 1; if (ii > mx) ii = mx;
        nrec = recs[ii];
      }
#pragma unroll
      for (int j = 0; j < 4; j++) {
        if (j >= rem) break;
        GAT1_EDGE(j)
      }
      float nxa0 = xa0, nxa1 = xa1, nxa2 = xa2, nxa3 = xa3, nxa4 = xa4;
      if (l < 8 && hn) {
        size_t sb = (size_t)__float_as_int(nrec.x) * 5;
        if (fl) { nxa0 = b2f(xh[sb]); nxa1 = b2f(xh[sb+1]); nxa2 = b2f(xh[sb+2]);
                  nxa3 = b2f(xh[sb+3]); nxa4 = b2f(xh[sb+4]); }
        else    { nxa0 = xf[sb]; nxa1 = xf[sb+1]; nxa2 = xf[sb+2];
                  nxa3 = xf[sb+3]; nxa4 = xf[sb+4]; }
      }
#pragma unroll
      for (int j = 4; j < 8; j++) {
        if (j >= rem) break;
        GAT1_EDGE(j)
      }
      rec = nrec;
      xa0 = nxa0; xa1 = nxa1; xa2 = nxa2; xa3 = nxa3; xa4 = nxa4;
    }
    {
      int row = w * 4 + nn;
#pragma unroll
      for (int q = 0; q < 4; q++) {
        float oo = acc[q] / s + biasv[q];
        oo = (oo > 0.f) ? oo : (__expf(oo) - 1.0f); // elu
        int ch = g * 64 + m + 16 * q;
        int byte = (row * 512 + ch * 2) ^ ((row & 7) << 4);
        *(unsigned short*)((char*)hS + byte) = f2b(oo);
      }
    }
  }
  __syncthreads();
  // MFMA lin2: wave w computes cols w*16..w*16+15 of xl2 and xr2 for 16 nodes.
  {
    int lo16 = l & 15, hi4 = l >> 4;
    f32x4 accL = {0.f, 0.f, 0.f, 0.f};
    f32x4 accR = {0.f, 0.f, 0.f, 0.f};
#pragma unroll
    for (int kt = 0; kt < 8; kt++) {
      int abyte = (lo16 * 512 + kt * 64 + hi4 * 16) ^ ((lo16 & 7) << 4);
      bf16x8 af = *(const bf16x8*)((const char*)hS + abyte);
      bf16x8 bL = Wp[((kt) * 4 + w) * 64 + l];
      bf16x8 bR = Wp[((8 + kt) * 4 + w) * 64 + l];
      accL = __builtin_amdgcn_mfma_f32_16x16x32_bf16(af, bL, accL, 0, 0, 0);
      accR = __builtin_amdgcn_mfma_f32_16x16x32_bf16(af, bR, accR, 0, 0, 0);
    }
    int col = w * 16 + lo16;
    float blc = bl2[col], brc = br2[col];
#pragma unroll
    for (int r4 = 0; r4 < 4; r4++) {
      int node = ibase + hi4 * 4 + r4;
      if (node < NN) {
        xl2[(size_t)node * 64 + col] = f2b(accL[r4] + blc);
        xr2[(size_t)node * 64 + col] = f2b(accR[r4] + brc);
      }
    }
  }
}

// GAT2 v12: r10-exact proven body (<105 µs): rolling prefetch (rec + xl2
// row), strided bf16 gathers at ch = m+16q (DO NOT vectorize to uint2 —
// proven r11 to trigger a 28-VGPR scratch-spill allocation, +75 µs),
// rep = i & 15 (r10's best-measured keying; blockIdx&15 measured +5 µs r12).
__global__ void k_gat2_v12(const float* We, const float* att, const float* bias,
                           const int* offs, const float4* recs,
                           const unsigned short* xl2, const unsigned short* xr2,
                           const int* batch, float* pooled_r, int* gcnt_r) {
  int i = blockIdx.x * 4 + (threadIdx.x >> 6);
  if (i >= NN) return;
  int t = threadIdx.x & 63;
  int r = t >> 4;
  int m = t & 15;
  float we0v[4], we1v[4], attv[4], xrcv[4], biasv[4];
#pragma unroll
  for (int q = 0; q < 4; q++) {
    int ch = m + 16 * q;
    we0v[q] = We[ch];
    we1v[q] = We[64 + ch];
    attv[q] = att[ch];
    biasv[q] = bias[ch];
    xrcv[q] = b2f(xr2[(size_t)i * 64 + ch]);
  }
  int p0 = offs[i], p1 = offs[i + 1];
  float4 rec;
  unsigned short c0, c1, c2, c3;
  {
    int e = p0 + r; if (e >= p1) e = p1 - 1;
    rec = recs[e];
    const unsigned short* xlp = xl2 + (size_t)__float_as_int(rec.x) * 64;
    c0 = xlp[m]; c1 = xlp[m + 16]; c2 = xlp[m + 32]; c3 = xlp[m + 48];
  }
  float s = 0.f;
  float acc[4] = {0.f, 0.f, 0.f, 0.f};
  for (int base = p0; base < p1; base += 4) {
    int nb = base + 4;
    bool hn = nb < p1;
    float4 nrec = rec;
    if (hn) { int e = nb + r; if (e >= p1) e = p1 - 1; nrec = recs[e]; }
    bool valid = base + r < p1;
    float xlv[4] = {b2f(c0), b2f(c1), b2f(c2), b2f(c3)};
    float v = 0.f;
#pragma unroll
    for (int q = 0; q < 4; q++) {
      float msg = xlv[q] + xrcv[q] + rec.y * we0v[q] + rec.z * we1v[q];
      msg = fmaxf(msg, 0.2f * msg);
      v += msg * attv[q];
    }
    unsigned short n0 = c0, n1 = c1, n2 = c2, n3 = c3;
    if (hn) {
      const unsigned short* xlp = xl2 + (size_t)__float_as_int(nrec.x) * 64;
      n0 = xlp[m]; n1 = xlp[m + 16]; n2 = xlp[m + 32]; n3 = xlp[m + 48];
    }
    v = row_red16(v);
    float w = valid ? __expf(v) : 0.f;
    s += w;
#pragma unroll
    for (int q = 0; q < 4; q++) acc[q] += w * xlv[q];
    rec = nrec; c0 = n0; c1 = n1; c2 = n2; c3 = n3;
  }
  s = cross_row(s);
#pragma unroll
  for (int q = 0; q < 4; q++) acc[q] = cross_row(acc[q]);
  if (r == 0) {
    int gsl = (int)(((unsigned)batch[i]) % (unsigned)GG);
    int rep = i & 15;
#pragma unroll
    for (int q = 0; q < 4; q++) {
      float o = acc[q] / s + biasv[q];
      o = (o > 0.f) ? o : (__expf(o) - 1.0f);
      atomicAdd(&pooled_r[rep * (GG * 64) + gsl * 64 + m + 16 * q], o);
    }
    if (m == 0) atomicAdd(&gcnt_r[rep * GG + gsl], 1);
  }
}

// GRU v10: poolsum + gin + GRU + classifier fused in one block.
__global__ void __launch_bounds__(768) k_gru_v10(
    const float* pooled_r, const int* gcnt_r,
    const float* Wi, const float* bi, const float* Wh, const float* bh,
    const float* Wc1, const float* bc1, const float* Wc2, const float* bc2,
    void* out) {
  __shared__ float pS[GG * 64];
  __shared__ float rcpS[GG];
  __shared__ float hS[64];
  __shared__ float ghS[192];
  __shared__ float giS[192];
  __shared__ float zc[32];
  int t = threadIdx.x;
  int j = t >> 2;
  int q = t & 3;
  float wh[16], wi[16];
#pragma unroll
  for (int kk = 0; kk < 16; kk++) {
    wh[kk] = Wh[(q * 16 + kk) * 192 + j];
    wi[kk] = Wi[(q * 16 + kk) * 192 + j];
  }
  float bhv = bh[j], biv = bi[j];
  for (int idx = t; idx < GG * 64; idx += 768) {
    float a = 0.f;
    for (int r = 0; r < 16; r++) a += pooled_r[r * (GG * 64) + idx];
    pS[idx] = a;
  }
  if (t < GG) {
    int a = 0;
    for (int r = 0; r < 16; r++) a += gcnt_r[r * GG + t];
    rcpS[t] = 1.0f / fmaxf((float)a, 1.0f);
  }
  if (t < 64) hS[t] = 0.f;
  __syncthreads();
  for (int ts = 0; ts < GG; ++ts) {
    float ag = 0.f, ai = 0.f;
    const float* pp = pS + ts * 64 + q * 16;
#pragma unroll
    for (int kk = 0; kk < 16; kk++) {
      ag += hS[q * 16 + kk] * wh[kk];
      ai += pp[kk] * wi[kk];
    }
    ag = quad_red4(ag);
    ai = quad_red4(ai);
    if (q == 0) {
      ghS[j] = ag + bhv;
      giS[j] = ai * rcpS[ts] + biv;
    }
    __syncthreads();
    if (t < 64) {
      float r = 1.f / (1.f + expf(-(giS[t] + ghS[t])));
      float z = 1.f / (1.f + expf(-(giS[64 + t] + ghS[64 + t])));
      float n = tanhf(giS[128 + t] + r * ghS[128 + t]);
      hS[t] = (1.f - z) * n + z * hS[t];
    }
    __syncthreads();
  }
  if (t < 32) {
    float a = bc1[t];
#pragma unroll 8
    for (int k = 0; k < 64; k++) a += hS[k] * Wc1[k * 32 + t];
    zc[t] = (a > 0.f) ? a : 0.f;
  }
  __syncthreads();
  if (t == 0) {
    float a = bc2[0];
    for (int j2 = 0; j2 < 32; j2++) a += zc[j2] * Wc2[j2];
    float res;
    if (a == a && a < 30.f && a > -30.f) res = 1.f / (1.f + expf(-a));
    else res = 0.4375f;
    write_dual(out, res);
  }
}

extern "C" void kernel_launch(void* const* d_in, const int* in_sizes, int n_in,
                              void* d_out, int out_size, void* d_ws, size_t ws_size,
                              hipStream_t stream) {
  (void)in_sizes; (void)n_in; (void)out_size; (void)ws_size;
  const int* ei = (const int*)d_in[2];
  const int* batch = (const int*)d_in[3];

  char* base = (char*)d_ws;
  size_t off = 0;
  int* deg = (int*)(base + off);        off += ((size_t)NN * 4 + 255) & ~(size_t)255;
  int* cursor = (int*)(base + off);     off += ((size_t)NN * 4 + 255) & ~(size_t)255;
  float* pooled_r = (float*)(base + off); off += ((size_t)16 * GG * 64 * 4 + 255) & ~(size_t)255;
  int* gcnt_r = (int*)(base + off);     off += ((size_t)16 * GG * 4 + 255) & ~(size_t)255;
  size_t zero_words = off / 4;
  int* flag = (int*)(base + off);       off += 256;
  int* offs = (int*)(base + off);       off += ((size_t)(NN + 1) * 4 + 255) & ~(size_t)255;
  float4* recs = (float4*)(base + off); off += ((size_t)EP * 16 + 255) & ~(size_t)255;
  unsigned short* xl2 = (unsigned short*)(base + off); off += ((size_t)NN * 64 * 2 + 255) & ~(size_t)255;
  unsigned short* xr2 = (unsigned short*)(base + off); off += ((size_t)NN * 64 * 2 + 255) & ~(size_t)255;
  unsigned short* Wp = (unsigned short*)(base + off); off += ((size_t)32768 * 2 + 255) & ~(size_t)255;

  // converted weights only (x, ea, Wl2, Wr2 read raw with inline flag-cvt)
  const int fidx[20]  = {4,5,6,7,8,9,10,12,14,15,16,17,18,19,20,21,22,23,24,25};
  const int fsize[20] = {1280,256,1280,256,512,256,256, 64, 64,
                         128,64,64, 12288,12288,192,192, 2048,32,32,1};
  float* F[26];
  Cvt20 cd;
  int total = 0;
  for (int i = 0; i < 20; i++) {
    F[fidx[i]] = (float*)(base + off);
    off += ((size_t)fsize[i] * 4 + 255) & ~(size_t)255;
    cd.src[i] = d_in[fidx[i]];
    cd.dst[i] = F[fidx[i]];
    cd.start[i] = total;
    total += fsize[i];
  }
  cd.start[20] = total;   // 31553

  int zb = (int)((zero_words + 255) / 256);
  k_init<<<zb, 256, 0, stream>>>((int*)d_ws, (int)zero_words,
                                 (const unsigned short*)d_in[0], flag);
  k_prep<<<CVTB + PKB + EEB, 256, 0, stream>>>(cd, flag, total, d_in[11], d_in[13], Wp,
                                               ei, deg);
  k_scan_v8<<<1, 1024, 0, stream>>>(deg, offs);
  k_scatter_v14<<<EEB, 256, 0, stream>>>(ei, d_in[1], flag, offs, cursor, recs);
  k_selfloop<<<(NN + 255) / 256, 256, 0, stream>>>(offs, recs);
  k_gat1_v18<<<(NN + 15) / 16, 256, 0, stream>>>(d_in[0], flag,
                                                 F[4], F[5], F[6], F[7], F[8], F[9], F[10],
                                                 (const bf16x8*)Wp, F[12], F[14],
                                                 offs, recs, xl2, xr2);
  k_gat2_v12<<<(NN + 3) / 4, 256, 0, stream>>>(F[15], F[16], F[17], offs, recs,
                                               xl2, xr2, batch, pooled_r, gcnt_r);
  k_gru_v10<<<1, 768, 0, stream>>>(pooled_r, gcnt_r, F[18], F[20], F[19], F[21],
                                   F[22], F[23], F[24], F[25], d_out);
}